// Round 1
// baseline (70.302 us; speedup 1.0000x reference)
//
#include <hip/hip_runtime.h>

#define NLEV 127.0f
#define QEPS 1e-8f

// ws layout (floats):
// [0]      absmax bits (as uint, atomicMax target)
// [1]      s (p_sf)
// [2..81]  M[5][16] composite matrix (already scaled by s)
// [82..86] c[5] composite bias (already scaled by s)

__global__ void init_ws(float* ws) {
    if (threadIdx.x == 0) ((unsigned int*)ws)[0] = 0u;
}

__global__ void __launch_bounds__(256) absmax_kernel(const float4* __restrict__ x,
                                                     int n4, float* ws) {
    float m = 0.f;
    int idx = blockIdx.x * blockDim.x + threadIdx.x;
    int stride = gridDim.x * blockDim.x;
    for (int i = idx; i < n4; i += stride) {
        float4 v = x[i];
        m = fmaxf(m, fmaxf(fmaxf(fabsf(v.x), fabsf(v.y)),
                           fmaxf(fabsf(v.z), fabsf(v.w))));
    }
    // wave (64-lane) reduce
    #pragma unroll
    for (int off = 32; off > 0; off >>= 1)
        m = fmaxf(m, __shfl_down(m, off, 64));
    __shared__ float sm[4];
    int wid = threadIdx.x >> 6;
    if ((threadIdx.x & 63) == 0) sm[wid] = m;
    __syncthreads();
    if (threadIdx.x == 0) {
        m = fmaxf(fmaxf(sm[0], sm[1]), fmaxf(sm[2], sm[3]));
        atomicMax((unsigned int*)ws, __float_as_uint(m));  // |x| >= 0: uint order == float order
    }
}

__device__ __forceinline__ float clipr(float v) {
    return fminf(fmaxf(rintf(v), -NLEV), NLEV);
}

// One block, 256 threads. Quantizes weights per the reference and composes the
// 4 affine layers into a single M[5][16], c[5] (both pre-scaled by s).
__global__ void __launch_bounds__(256) prep_kernel(
        const float* __restrict__ w0, const float* __restrict__ b0,
        const float* __restrict__ w2, const float* __restrict__ b2,
        const float* __restrict__ w4, const float* __restrict__ b4,
        const float* __restrict__ w6, const float* __restrict__ b6,
        float* ws) {
    __shared__ float T[64][16], Tn[64][16];
    __shared__ float cc[64], cn[64], sfv[64], bi[64];
    __shared__ float Wq[64 * 64];
    __shared__ float s_sh;
    const int t = threadIdx.x;

    if (t == 0) {
        float am = __uint_as_float(((const unsigned int*)ws)[0]);
        s_sh = fmaxf(am / NLEV, QEPS);
    }
    for (int i = t; i < 64 * 16; i += 256) {
        int r = i >> 4, ci = i & 15;
        T[r][ci] = (r == ci) ? 1.f : 0.f;
    }
    if (t < 64) cc[t] = 0.f;
    __syncthreads();
    const float s = s_sh;

    const float* Ws[4] = {w0, w2, w4, w6};
    const float* Bs[4] = {b0, b2, b4, b6};
    const int    Od[4] = {64, 32, 32, 5};
    const int    Fd[4] = {16, 64, 32, 32};

    for (int L = 0; L < 4; ++L) {
        const int O = Od[L], F = Fd[L];
        const float* W = Ws[L];
        const float* Bb = Bs[L];
        // per-output-channel scale + quantized bias (matches reference exactly)
        if (t < O) {
            float am = 0.f;
            for (int j = 0; j < F; ++j) am = fmaxf(am, fabsf(W[t * F + j]));
            float sf = fmaxf(am / NLEV, QEPS);
            sfv[t] = sf;
            bi[t]  = clipr(Bb[t] / (sf * s));
        }
        __syncthreads();
        for (int i = t; i < O * F; i += 256)
            Wq[i] = clipr(W[i] / sfv[i / F]);
        __syncthreads();
        // compose: Tn = diag(sfv) * Wq * T ; cn = diag(sfv) * (Wq * cc + bi)
        for (int i = t; i < O * 16; i += 256) {
            int o = i >> 4, col = i & 15;
            float acc = 0.f;
            for (int j = 0; j < F; ++j) acc += Wq[o * F + j] * T[j][col];
            Tn[o][col] = acc * sfv[o];
        }
        if (t < O) {
            float acc = bi[t];
            for (int j = 0; j < F; ++j) acc += Wq[t * F + j] * cc[j];
            cn[t] = acc * sfv[t];
        }
        __syncthreads();
        for (int i = t; i < O * 16; i += 256) T[i >> 4][i & 15] = Tn[i >> 4][i & 15];
        if (t < O) cc[t] = cn[t];
        __syncthreads();
    }
    // final output = x_int^4 * s  → fold s into M and c
    if (t < 80) ws[2 + t] = T[t >> 4][t & 15] * s;
    if (t < 5)  ws[82 + t] = cc[t] * s;
    if (t == 0) ws[1] = s;
}

__global__ void __launch_bounds__(256) main_kernel(const float* __restrict__ x,
                                                   const float* __restrict__ ws,
                                                   float* __restrict__ out, int B) {
    __shared__ float M[5][16];
    __shared__ float c[5];
    __shared__ float s_sh;
    const int t = threadIdx.x;
    if (t < 80) M[t >> 4][t & 15] = ws[2 + t];
    if (t < 5)  c[t] = ws[82 + t];
    if (t == 0) s_sh = ws[1];
    __syncthreads();
    const float s = s_sh;

    int idx = blockIdx.x * blockDim.x + t;
    int stride = gridDim.x * blockDim.x;
    for (int r = idx; r < B; r += stride) {
        const float4* xr = (const float4*)(x + (size_t)r * 16);
        float q[16];
        #pragma unroll
        for (int v = 0; v < 4; ++v) {
            float4 vv = xr[v];
            q[v * 4 + 0] = fminf(fmaxf(rintf(vv.x / s), -NLEV), NLEV);
            q[v * 4 + 1] = fminf(fmaxf(rintf(vv.y / s), -NLEV), NLEV);
            q[v * 4 + 2] = fminf(fmaxf(rintf(vv.z / s), -NLEV), NLEV);
            q[v * 4 + 3] = fminf(fmaxf(rintf(vv.w / s), -NLEV), NLEV);
        }
        float o[5];
        #pragma unroll
        for (int oo = 0; oo < 5; ++oo) {
            float acc = c[oo];
            #pragma unroll
            for (int i = 0; i < 16; ++i) acc = fmaf(q[i], M[oo][i], acc);
            o[oo] = acc;
        }
        float* orow = out + (size_t)r * 5;
        orow[0] = o[0]; orow[1] = o[1]; orow[2] = o[2]; orow[3] = o[3]; orow[4] = o[4];
    }
}

extern "C" void kernel_launch(void* const* d_in, const int* in_sizes, int n_in,
                              void* d_out, int out_size, void* d_ws, size_t ws_size,
                              hipStream_t stream) {
    const float* x  = (const float*)d_in[0];
    const float* w0 = (const float*)d_in[1];
    const float* b0 = (const float*)d_in[2];
    const float* w2 = (const float*)d_in[3];
    const float* b2 = (const float*)d_in[4];
    const float* w4 = (const float*)d_in[5];
    const float* b4 = (const float*)d_in[6];
    const float* w6 = (const float*)d_in[7];
    const float* b6 = (const float*)d_in[8];
    float* out = (float*)d_out;
    float* ws  = (float*)d_ws;

    const int B  = in_sizes[0] / 16;
    const int n4 = B * 4;  // float4 count of x

    init_ws<<<1, 64, 0, stream>>>(ws);
    absmax_kernel<<<2048, 256, 0, stream>>>((const float4*)x, n4, ws);
    prep_kernel<<<1, 256, 0, stream>>>(w0, b0, w2, b2, w4, b4, w6, b6, ws);
    main_kernel<<<2048, 256, 0, stream>>>(x, ws, out, B);
}

// Round 2
// 55.258 us; speedup vs baseline: 1.2722x; 1.2722x over previous
//
#include <hip/hip_runtime.h>

#define NLEV 127.0f
#define QEPS 1e-8f
#define ABS_BLOCKS 1024

// ws layout (floats):
// [1]        inv_s
// [2..81]    M[5][16] composite matrix (pre-scaled by s)
// [82..86]   c[5] composite bias (pre-scaled by s)
// [128..128+ABS_BLOCKS)  per-block |x| partial maxima

__device__ __forceinline__ float max4(float4 v) {
    return fmaxf(fmaxf(fabsf(v.x), fabsf(v.y)), fmaxf(fabsf(v.z), fabsf(v.w)));
}

__global__ void __launch_bounds__(256) absmax_part(const float4* __restrict__ x,
                                                   int n4, float* __restrict__ ws) {
    const int tid = blockIdx.x * blockDim.x + threadIdx.x;
    const int stride = gridDim.x * blockDim.x;
    float m0 = 0.f, m1 = 0.f, m2 = 0.f, m3 = 0.f;
    int i = tid;
    for (; i + 3 * stride < n4; i += 4 * stride) {
        float4 a = x[i];
        float4 b = x[i + stride];
        float4 c = x[i + 2 * stride];
        float4 d = x[i + 3 * stride];
        m0 = fmaxf(m0, max4(a));
        m1 = fmaxf(m1, max4(b));
        m2 = fmaxf(m2, max4(c));
        m3 = fmaxf(m3, max4(d));
    }
    for (; i < n4; i += stride) m0 = fmaxf(m0, max4(x[i]));
    float m = fmaxf(fmaxf(m0, m1), fmaxf(m2, m3));
    #pragma unroll
    for (int off = 32; off > 0; off >>= 1)
        m = fmaxf(m, __shfl_down(m, off, 64));
    __shared__ float sm[4];
    if ((threadIdx.x & 63) == 0) sm[threadIdx.x >> 6] = m;
    __syncthreads();
    if (threadIdx.x == 0)
        ws[128 + blockIdx.x] = fmaxf(fmaxf(sm[0], sm[1]), fmaxf(sm[2], sm[3]));
}

__device__ __forceinline__ float clipr(float v) {
    return fminf(fmaxf(rintf(v), -NLEV), NLEV);
}

// One block, 256 threads: reduce partials -> s; quantize weights per reference;
// compose the 4 affine layers into M[5][16], c[5] (pre-scaled by s).
__global__ void __launch_bounds__(256) prep_kernel(
        const float* __restrict__ w0, const float* __restrict__ b0,
        const float* __restrict__ w2, const float* __restrict__ b2,
        const float* __restrict__ w4, const float* __restrict__ b4,
        const float* __restrict__ w6, const float* __restrict__ b6,
        float* ws) {
    __shared__ float T[64][16], Tn[64][16];
    __shared__ float cc[64], cn[64], sfv[64], bi[64];
    __shared__ float Wq[64 * 64];
    __shared__ float s_sh, red[4];
    const int t = threadIdx.x;

    // reduce the ABS_BLOCKS partial maxima
    float pm = 0.f;
    for (int i = t; i < ABS_BLOCKS; i += 256) pm = fmaxf(pm, ws[128 + i]);
    #pragma unroll
    for (int off = 32; off > 0; off >>= 1)
        pm = fmaxf(pm, __shfl_down(pm, off, 64));
    if ((t & 63) == 0) red[t >> 6] = pm;
    __syncthreads();
    if (t == 0) {
        float am = fmaxf(fmaxf(red[0], red[1]), fmaxf(red[2], red[3]));
        s_sh = fmaxf(am / NLEV, QEPS);
    }
    for (int i = t; i < 64 * 16; i += 256) {
        int r = i >> 4, ci = i & 15;
        T[r][ci] = (r == ci) ? 1.f : 0.f;
    }
    if (t < 64) cc[t] = 0.f;
    __syncthreads();
    const float s = s_sh;

    const float* Ws[4] = {w0, w2, w4, w6};
    const float* Bs[4] = {b0, b2, b4, b6};
    const int    Od[4] = {64, 32, 32, 5};
    const int    Fd[4] = {16, 64, 32, 32};

    for (int L = 0; L < 4; ++L) {
        const int O = Od[L], F = Fd[L];
        const float* W = Ws[L];
        const float* Bb = Bs[L];
        if (t < O) {
            float am = 0.f;
            for (int j = 0; j < F; ++j) am = fmaxf(am, fabsf(W[t * F + j]));
            float sf = fmaxf(am / NLEV, QEPS);
            sfv[t] = sf;
            bi[t]  = clipr(Bb[t] / (sf * s));
        }
        __syncthreads();
        for (int i = t; i < O * F; i += 256)
            Wq[i] = clipr(W[i] / sfv[i / F]);
        __syncthreads();
        for (int i = t; i < O * 16; i += 256) {
            int o = i >> 4, col = i & 15;
            float acc = 0.f;
            for (int j = 0; j < F; ++j) acc += Wq[o * F + j] * T[j][col];
            Tn[o][col] = acc * sfv[o];
        }
        if (t < O) {
            float acc = bi[t];
            for (int j = 0; j < F; ++j) acc += Wq[t * F + j] * cc[j];
            cn[t] = acc * sfv[t];
        }
        __syncthreads();
        for (int i = t; i < O * 16; i += 256) T[i >> 4][i & 15] = Tn[i >> 4][i & 15];
        if (t < O) cc[t] = cn[t];
        __syncthreads();
    }
    if (t < 80) ws[2 + t] = T[t >> 4][t & 15] * s;
    if (t < 5)  ws[82 + t] = cc[t] * s;
    if (t == 0) ws[1] = 1.0f / s;
}

// 4 rows per thread: 16 contiguous float4 reads (256B/lane), 5 float4 stores (80B/lane).
__global__ void __launch_bounds__(256) main_kernel(const float4* __restrict__ x4,
                                                   const float* __restrict__ ws,
                                                   float4* __restrict__ out4, int Bq) {
    __shared__ float M[5][16];
    __shared__ float c[5];
    __shared__ float inv_sh;
    const int t = threadIdx.x;
    if (t < 80) M[t >> 4][t & 15] = ws[2 + t];
    if (t < 5)  c[t] = ws[82 + t];
    if (t == 0) inv_sh = ws[1];
    __syncthreads();
    const float inv_s = inv_sh;

    int g = blockIdx.x * blockDim.x + t;
    int stride = gridDim.x * blockDim.x;
    for (int grp = g; grp < Bq; grp += stride) {
        const float4* xr = x4 + (size_t)grp * 16;
        float flat[20];
        #pragma unroll
        for (int r = 0; r < 4; ++r) {
            float q[16];
            #pragma unroll
            for (int v = 0; v < 4; ++v) {
                float4 vv = xr[r * 4 + v];
                q[v * 4 + 0] = fminf(fmaxf(rintf(vv.x * inv_s), -NLEV), NLEV);
                q[v * 4 + 1] = fminf(fmaxf(rintf(vv.y * inv_s), -NLEV), NLEV);
                q[v * 4 + 2] = fminf(fmaxf(rintf(vv.z * inv_s), -NLEV), NLEV);
                q[v * 4 + 3] = fminf(fmaxf(rintf(vv.w * inv_s), -NLEV), NLEV);
            }
            #pragma unroll
            for (int oo = 0; oo < 5; ++oo) {
                float acc = c[oo];
                #pragma unroll
                for (int i = 0; i < 16; ++i) acc = fmaf(q[i], M[oo][i], acc);
                flat[r * 5 + oo] = acc;
            }
        }
        float4* orow = out4 + (size_t)grp * 5;
        orow[0] = make_float4(flat[0],  flat[1],  flat[2],  flat[3]);
        orow[1] = make_float4(flat[4],  flat[5],  flat[6],  flat[7]);
        orow[2] = make_float4(flat[8],  flat[9],  flat[10], flat[11]);
        orow[3] = make_float4(flat[12], flat[13], flat[14], flat[15]);
        orow[4] = make_float4(flat[16], flat[17], flat[18], flat[19]);
    }
}

extern "C" void kernel_launch(void* const* d_in, const int* in_sizes, int n_in,
                              void* d_out, int out_size, void* d_ws, size_t ws_size,
                              hipStream_t stream) {
    const float* x  = (const float*)d_in[0];
    const float* w0 = (const float*)d_in[1];
    const float* b0 = (const float*)d_in[2];
    const float* w2 = (const float*)d_in[3];
    const float* b2 = (const float*)d_in[4];
    const float* w4 = (const float*)d_in[5];
    const float* b4 = (const float*)d_in[6];
    const float* w6 = (const float*)d_in[7];
    const float* b6 = (const float*)d_in[8];
    float* ws = (float*)d_ws;

    const int B  = in_sizes[0] / 16;
    const int n4 = B * 4;      // float4 elements of x
    const int Bq = B / 4;      // 4-row groups (B is a multiple of 4 here)

    absmax_part<<<ABS_BLOCKS, 256, 0, stream>>>((const float4*)x, n4, ws);
    prep_kernel<<<1, 256, 0, stream>>>(w0, b0, w2, b2, w4, b4, w6, b6, ws);
    main_kernel<<<1024, 256, 0, stream>>>((const float4*)x, ws, (float4*)d_out, Bq);
}